// Round 7
// baseline (400.903 us; speedup 1.0000x reference)
//
#include <hip/hip_runtime.h>
#include <hip/hip_bf16.h>
#include <stdint.h>

#define N_NODES 100000
#define N_EDGES 3200000
#define IN_F 256
#define HID 128
#define OUT_F 8

#define NB   391        // node buckets of 256
#define PASS 6144       // edges staged per k_part block (33KB LDS -> 4 blk/CU)
#define CAP  10240      // k_csr LDS stage capacity

typedef short short8 __attribute__((ext_vector_type(8)));
typedef float f32x4 __attribute__((ext_vector_type(4)));
typedef float f32x2 __attribute__((ext_vector_type(2)));

// bf16 pack helpers (RNE)
__device__ __forceinline__ uint32_t pk_bf16(float a, float b) {
    uint32_t ua = __float_as_uint(a);
    uint32_t ub = __float_as_uint(b);
    ua = (ua + 0x7fff + ((ua >> 16) & 1)) >> 16;
    ub = (ub + 0x7fff + ((ub >> 16) & 1)) & 0xffff0000u;
    return ua | ub;
}

// ---------------------------------------------------------------------------
// Bucket histogram (LDS-aggregated, int4 edge reads)
// ---------------------------------------------------------------------------
__global__ __launch_bounds__(256) void k_bhist(const int* __restrict__ dst,
                                               int* __restrict__ gcnt, int E) {
    __shared__ int lb[NB];
    for (int i = threadIdx.x; i < NB; i += 256) lb[i] = 0;
    __syncthreads();
    int stride = gridDim.x * 256;
    const int4* d4 = (const int4*)dst;
    for (int e = blockIdx.x * 256 + threadIdx.x; e < E / 4; e += stride) {
        int4 d = d4[e];
        atomicAdd(&lb[d.x >> 8], 1);
        atomicAdd(&lb[d.y >> 8], 1);
        atomicAdd(&lb[d.z >> 8], 1);
        atomicAdd(&lb[d.w >> 8], 1);
    }
    __syncthreads();
    for (int i = threadIdx.x; i < NB; i += 256) {
        int c = lb[i];
        if (c) atomicAdd(&gcnt[i * 64], c);
    }
}

__global__ __launch_bounds__(512) void k_bscan(const int* __restrict__ gcnt,
                                               int* __restrict__ bbase,
                                               int* __restrict__ gcur) {
    __shared__ int sc[512];
    int tid = threadIdx.x;
    int v = (tid < NB) ? gcnt[tid * 64] : 0;
    sc[tid] = v;
    __syncthreads();
    for (int d = 1; d < 512; d <<= 1) {
        int t = (tid >= d) ? sc[tid - d] : 0;
        __syncthreads();
        sc[tid] += t;
        __syncthreads();
    }
    int excl = sc[tid] - v;
    if (tid <= NB) bbase[tid] = excl;
    if (tid < NB) gcur[tid * 64] = excl;
}

// ---------------------------------------------------------------------------
// Partition edges into bucket-contiguous regions (LDS-staged flush), 512 thr
// ---------------------------------------------------------------------------
__global__ __launch_bounds__(512) void k_part(const int* __restrict__ src,
                                              const int* __restrict__ dst,
                                              int* __restrict__ gcur,
                                              uint32_t* __restrict__ epk, int E) {
    __shared__ int lcnt[NB], loff[NB], ladj[NB], lcur[NB];
    __shared__ int sc[512];
    __shared__ uint32_t stage[PASS];
    int tid = threadIdx.x;
    int e0 = blockIdx.x * PASS;

    for (int i = tid; i < NB; i += 512) { lcnt[i] = 0; lcur[i] = 0; }
    __syncthreads();
    for (int i = tid; i < PASS; i += 512) {
        int e = e0 + i;
        if (e < E) atomicAdd(&lcnt[dst[e] >> 8], 1);
    }
    __syncthreads();
    int v = (tid < NB) ? lcnt[tid] : 0;
    sc[tid] = v;
    __syncthreads();
    for (int d = 1; d < 512; d <<= 1) {
        int t = (tid >= d) ? sc[tid - d] : 0;
        __syncthreads();
        sc[tid] += t;
        __syncthreads();
    }
    if (tid < NB) loff[tid] = sc[tid] - v;
    __syncthreads();
    if (tid < NB) {
        int len = lcnt[tid];
        if (len > 0) ladj[tid] = atomicAdd(&gcur[tid * 64], len);
    }
    __syncthreads();
    for (int i = tid; i < PASS; i += 512) {
        int e = e0 + i;
        if (e < E) {
            int d = dst[e];
            int b = d >> 8;
            int r = atomicAdd(&lcur[b], 1);
            stage[loff[b] + r] = (uint32_t)src[e] | ((uint32_t)(d & 255) << 17);
        }
    }
    __syncthreads();
    int wv = tid >> 6, ln = tid & 63;
    for (int b = wv; b < NB; b += 8) {
        int len = lcnt[b], lo = loff[b], gb = ladj[b];
        for (int j = ln; j < len; j += 64) epk[gb + j] = stage[lo + j];
    }
}

// ---------------------------------------------------------------------------
// Per-bucket CSR finalize: offs/cnt/dinv + node-sorted ssrc. 1024 threads.
// ---------------------------------------------------------------------------
__global__ __launch_bounds__(1024) void k_csr(const uint32_t* __restrict__ epk,
                                              const int* __restrict__ bbase,
                                              int* __restrict__ offs,
                                              int* __restrict__ cnt,
                                              float* __restrict__ dinv,
                                              int* __restrict__ ssrc, int N) {
    __shared__ int lcnt[256], lcur[256], loff[256];
    __shared__ uint32_t stage[CAP];
    int tid = threadIdx.x, b = blockIdx.x;
    int base = bbase[b], m = bbase[b + 1] - base;

    if (tid < 256) lcnt[tid] = 0;
    __syncthreads();
    for (int i = tid; i < m; i += 1024)
        atomicAdd(&lcnt[(epk[base + i] >> 17) & 255], 1);
    __syncthreads();
    int v = (tid < 256) ? lcnt[tid] : 0;
    if (tid < 256) loff[tid] = v;
    __syncthreads();
    for (int d = 1; d < 256; d <<= 1) {
        int t = (tid >= d && tid < 256) ? loff[tid - d] : 0;
        __syncthreads();
        if (tid < 256) loff[tid] += t;
        __syncthreads();
    }
    int excl = (tid < 256) ? (loff[tid] - v) : 0;
    __syncthreads();
    if (tid < 256) {
        loff[tid] = excl;
        lcur[tid] = 0;
        int node = b * 256 + tid;
        if (node < N) {
            offs[node] = base + excl;
            cnt[node] = v;
            dinv[node] = rsqrtf((float)(v + 1));
        }
    }
    __syncthreads();
    if (m <= CAP) {
        for (int i = tid; i < m; i += 1024) {
            uint32_t u = epk[base + i];
            int ld = (u >> 17) & 255;
            int r = atomicAdd(&lcur[ld], 1);
            stage[loff[ld] + r] = u & 0x1FFFF;
        }
        __syncthreads();
        for (int i = tid; i < m; i += 1024) ssrc[base + i] = (int)stage[i];
    } else {
        for (int i = tid; i < m; i += 1024) {
            uint32_t u = epk[base + i];
            int ld = (u >> 17) & 255;
            int r = atomicAdd(&lcur[ld], 1);
            ssrc[base + loff[ld] + r] = (int)(u & 0x1FFFF);
        }
    }
}

// ---------------------------------------------------------------------------
// W1 [256][128] fp32 -> W1bf [128][256] bf16 (transposed, n-major)
// ---------------------------------------------------------------------------
__global__ __launch_bounds__(256) void k_wcast(const float* __restrict__ W1,
                                               ushort* __restrict__ Wbf) {
    __shared__ ushort T[128][33];
    int t = threadIdx.x;
    int k0 = blockIdx.x * 32;
    for (int idx = t; idx < 32 * 128; idx += 256) {
        int k = idx >> 7, n = idx & 127;
        uint32_t uv = __float_as_uint(W1[(size_t)(k0 + k) * HID + n]);
        uv = (uv + 0x7fff + ((uv >> 16) & 1)) >> 16;
        T[n][k] = (ushort)uv;
    }
    __syncthreads();
    for (int idx = t; idx < 32 * 128; idx += 256) {
        int n = idx >> 5, k = idx & 31;
        Wbf[(size_t)n * IN_F + k0 + k] = T[n][k];
    }
}

// ---------------------------------------------------------------------------
// GEMM1 (MFMA bf16): Hs8[100000][128](fp8 e4m3) = (X @ W1) * dinv[row]
// ---------------------------------------------------------------------------
__global__ __launch_bounds__(256) void k_gemm1(const float* __restrict__ X,
                                               const ushort* __restrict__ Wbf,
                                               const float* __restrict__ dinv,
                                               uint32_t* __restrict__ Hs8, int M) {
    __shared__ uint32_t As[64 * 20];    // 64 rows x 40 bf16
    __shared__ uint32_t Bs[128 * 20];   // 128 n-rows x 40 bf16
    __shared__ float st[4][16 * 132];   // per-wave epilogue stage
    int t = threadIdx.x;
    int lane = t & 63, w = t >> 6;
    int q = lane >> 4, c16 = lane & 15;
    int row0 = blockIdx.x * 64;

    int ar = t >> 2, a4 = (t & 3);
    int grow = row0 + ar; if (grow >= M) grow = M - 1;
    const float* xrow = X + (size_t)grow * IN_F;
    int bn = t >> 1, b1h = (t & 1);
    const ushort* wrow = Wbf + (size_t)bn * IN_F;

    f32x4 acc[8];
    #pragma unroll
    for (int j = 0; j < 8; j++) acc[j] = (f32x4){0.f, 0.f, 0.f, 0.f};

    for (int kc = 0; kc < IN_F; kc += 32) {
        float4 x0 = *(const float4*)(xrow + kc + a4 * 8);
        float4 x1 = *(const float4*)(xrow + kc + a4 * 8 + 4);
        uint4 wv0 = *(const uint4*)(wrow + kc + b1h * 16);
        uint4 wv1 = *(const uint4*)(wrow + kc + b1h * 16 + 8);
        __syncthreads();
        *(uint2*)&As[ar * 20 + a4 * 4]     = make_uint2(pk_bf16(x0.x, x0.y), pk_bf16(x0.z, x0.w));
        *(uint2*)&As[ar * 20 + a4 * 4 + 2] = make_uint2(pk_bf16(x1.x, x1.y), pk_bf16(x1.z, x1.w));
        *(uint4*)&Bs[bn * 20 + b1h * 8]     = wv0;
        *(uint4*)&Bs[bn * 20 + b1h * 8 + 4] = wv1;
        __syncthreads();
        short8 af = *(const short8*)&As[(w * 16 + c16) * 20 + q * 4];
        #pragma unroll
        for (int j = 0; j < 8; j++) {
            short8 bf = *(const short8*)&Bs[(j * 16 + c16) * 20 + q * 4];
            acc[j] = __builtin_amdgcn_mfma_f32_16x16x32_bf16(af, bf, acc[j], 0, 0, 0);
        }
    }
    float dv[4];
    #pragma unroll
    for (int r = 0; r < 4; r++) {
        int gr = row0 + w * 16 + q * 4 + r;
        dv[r] = (gr < M) ? dinv[gr] : 0.f;
    }
    #pragma unroll
    for (int j = 0; j < 8; j++)
        #pragma unroll
        for (int r = 0; r < 4; r++)
            st[w][(q * 4 + r) * 132 + j * 16 + c16] = acc[j][r] * dv[r];
    __syncthreads();
    #pragma unroll
    for (int p = 0; p < 4; p++) {
        int rr = p * 4 + q;
        int gr = row0 + w * 16 + rr;
        float4 v0 = *(const float4*)&st[w][rr * 132 + c16 * 8];
        float4 v1 = *(const float4*)&st[w][rr * 132 + c16 * 8 + 4];
        uint32_t lo = 0, hi = 0;
        lo = __builtin_amdgcn_cvt_pk_fp8_f32(v0.x, v0.y, lo, false);
        lo = __builtin_amdgcn_cvt_pk_fp8_f32(v0.z, v0.w, lo, true);
        hi = __builtin_amdgcn_cvt_pk_fp8_f32(v1.x, v1.y, hi, false);
        hi = __builtin_amdgcn_cvt_pk_fp8_f32(v1.z, v1.w, hi, true);
        if (gr < M) *(uint2*)&Hs8[(size_t)gr * 32 + c16 * 2] = make_uint2(lo, hi);
    }
}

// ---------------------------------------------------------------------------
// Aggregation layer 1 + ReLU + fused GEMM2: wave per node, fp8 rows (128B).
// Half-wave per edge, 8 loads in flight; packed f32x2 accumulate.
// Epilogue: each lane holds its fixed 4x4 W2 patch in REGISTERS (no LDS, no
// bank conflicts): wreg[i] = W2[c*4+i][f0..f0+3], f0 = 4*half.
// ---------------------------------------------------------------------------
__global__ __launch_bounds__(256) void k_agg1(const uint32_t* __restrict__ hs,
                                              const int* __restrict__ offs,
                                              const int* __restrict__ cnt,
                                              const float* __restrict__ dinv,
                                              const int* __restrict__ ssrc,
                                              const float* __restrict__ b1,
                                              const float* __restrict__ W2,
                                              float* __restrict__ h2s, int N) {
    int t = threadIdx.x;
    int wid = (blockIdx.x * 256 + t) >> 6;
    int lane = t & 63;
    if (wid >= N) return;
    int h = lane >> 5, c = lane & 31;
    int f0 = h * 4;
    // per-lane W2 patch (16 regs); 4KB table, L2-resident
    float4 wr0 = *(const float4*)&W2[(c * 4 + 0) * OUT_F + f0];
    float4 wr1 = *(const float4*)&W2[(c * 4 + 1) * OUT_F + f0];
    float4 wr2 = *(const float4*)&W2[(c * 4 + 2) * OUT_F + f0];
    float4 wr3 = *(const float4*)&W2[(c * 4 + 3) * OUT_F + f0];
    float dv = dinv[wid];
    f32x2 s01 = {0.f, 0.f}, s23 = {0.f, 0.f};
    if (h == 0) {
        uint32_t u = hs[(size_t)wid * 32 + c];
        s01 = __builtin_amdgcn_cvt_pk_f32_fp8(u, false);
        s23 = __builtin_amdgcn_cvt_pk_f32_fp8(u, true);
    }
    int beg = offs[wid], n = cnt[wid];
    const int* sp = ssrc + beg;
    int j = h;
    for (; j + 14 < n; j += 16) {
        int e0 = sp[j],      e1 = sp[j + 2],  e2 = sp[j + 4],  e3 = sp[j + 6];
        int e4 = sp[j + 8],  e5 = sp[j + 10], e6 = sp[j + 12], e7 = sp[j + 14];
        uint32_t u0 = hs[(size_t)e0 * 32 + c];
        uint32_t u1 = hs[(size_t)e1 * 32 + c];
        uint32_t u2 = hs[(size_t)e2 * 32 + c];
        uint32_t u3 = hs[(size_t)e3 * 32 + c];
        uint32_t u4 = hs[(size_t)e4 * 32 + c];
        uint32_t u5 = hs[(size_t)e5 * 32 + c];
        uint32_t u6 = hs[(size_t)e6 * 32 + c];
        uint32_t u7 = hs[(size_t)e7 * 32 + c];
        s01 += __builtin_amdgcn_cvt_pk_f32_fp8(u0, false); s23 += __builtin_amdgcn_cvt_pk_f32_fp8(u0, true);
        s01 += __builtin_amdgcn_cvt_pk_f32_fp8(u1, false); s23 += __builtin_amdgcn_cvt_pk_f32_fp8(u1, true);
        s01 += __builtin_amdgcn_cvt_pk_f32_fp8(u2, false); s23 += __builtin_amdgcn_cvt_pk_f32_fp8(u2, true);
        s01 += __builtin_amdgcn_cvt_pk_f32_fp8(u3, false); s23 += __builtin_amdgcn_cvt_pk_f32_fp8(u3, true);
        s01 += __builtin_amdgcn_cvt_pk_f32_fp8(u4, false); s23 += __builtin_amdgcn_cvt_pk_f32_fp8(u4, true);
        s01 += __builtin_amdgcn_cvt_pk_f32_fp8(u5, false); s23 += __builtin_amdgcn_cvt_pk_f32_fp8(u5, true);
        s01 += __builtin_amdgcn_cvt_pk_f32_fp8(u6, false); s23 += __builtin_amdgcn_cvt_pk_f32_fp8(u6, true);
        s01 += __builtin_amdgcn_cvt_pk_f32_fp8(u7, false); s23 += __builtin_amdgcn_cvt_pk_f32_fp8(u7, true);
    }
    for (; j + 6 < n; j += 8) {
        int e0 = sp[j], e1 = sp[j + 2], e2 = sp[j + 4], e3 = sp[j + 6];
        uint32_t u0 = hs[(size_t)e0 * 32 + c];
        uint32_t u1 = hs[(size_t)e1 * 32 + c];
        uint32_t u2 = hs[(size_t)e2 * 32 + c];
        uint32_t u3 = hs[(size_t)e3 * 32 + c];
        s01 += __builtin_amdgcn_cvt_pk_f32_fp8(u0, false); s23 += __builtin_amdgcn_cvt_pk_f32_fp8(u0, true);
        s01 += __builtin_amdgcn_cvt_pk_f32_fp8(u1, false); s23 += __builtin_amdgcn_cvt_pk_f32_fp8(u1, true);
        s01 += __builtin_amdgcn_cvt_pk_f32_fp8(u2, false); s23 += __builtin_amdgcn_cvt_pk_f32_fp8(u2, true);
        s01 += __builtin_amdgcn_cvt_pk_f32_fp8(u3, false); s23 += __builtin_amdgcn_cvt_pk_f32_fp8(u3, true);
    }
    for (; j < n; j += 2) {
        uint32_t u = hs[(size_t)sp[j] * 32 + c];
        s01 += __builtin_amdgcn_cvt_pk_f32_fp8(u, false);
        s23 += __builtin_amdgcn_cvt_pk_f32_fp8(u, true);
    }
    // combine halves (both halves end with identical full sums)
    s01[0] += __shfl_xor(s01[0], 32);
    s01[1] += __shfl_xor(s01[1], 32);
    s23[0] += __shfl_xor(s23[0], 32);
    s23[1] += __shfl_xor(s23[1], 32);
    // bias + ReLU (fp32)
    float4 bb = *(const float4*)(b1 + c * 4);
    float o0 = fmaxf(fmaf(s01[0], dv, bb.x), 0.f);
    float o1 = fmaxf(fmaf(s01[1], dv, bb.y), 0.f);
    float o2 = fmaxf(fmaf(s23[0], dv, bb.z), 0.f);
    float o3 = fmaxf(fmaf(s23[1], dv, bb.w), 0.f);
    // fused GEMM2 partial from registers: p[f] = sum_i o_i * W2[c*4+i][f0+f]
    float p0 = o0 * wr0.x + o1 * wr1.x + o2 * wr2.x + o3 * wr3.x;
    float p1 = o0 * wr0.y + o1 * wr1.y + o2 * wr2.y + o3 * wr3.y;
    float p2 = o0 * wr0.z + o1 * wr1.z + o2 * wr2.z + o3 * wr3.z;
    float p3 = o0 * wr0.w + o1 * wr1.w + o2 * wr2.w + o3 * wr3.w;
    #pragma unroll
    for (int d = 1; d < 32; d <<= 1) {
        p0 += __shfl_xor(p0, d);
        p1 += __shfl_xor(p1, d);
        p2 += __shfl_xor(p2, d);
        p3 += __shfl_xor(p3, d);
    }
    if (c == 0) {
        float4 ov = make_float4(p0 * dv, p1 * dv, p2 * dv, p3 * dv);
        *(float4*)&h2s[(size_t)wid * OUT_F + f0] = ov;
    }
}

// ---------------------------------------------------------------------------
// Aggregation layer 2 + bias + log_softmax, fused; 4-deep gather MLP.
// ---------------------------------------------------------------------------
__global__ __launch_bounds__(256) void k_agg2(const float* __restrict__ h2s,
                                              const int* __restrict__ offs,
                                              const int* __restrict__ cnt,
                                              const float* __restrict__ dinv,
                                              const int* __restrict__ ssrc,
                                              const float* __restrict__ b2,
                                              float* __restrict__ out, int N) {
    int wid = (blockIdx.x * 256 + threadIdx.x) >> 6;
    int lane = threadIdx.x & 63;
    if (wid >= N) return;
    int f = lane & 7, g = lane >> 3;
    float dv = dinv[wid];
    int beg = offs[wid], n = cnt[wid];
    const int* sp = ssrc + beg;
    float acc = 0.f;
    int j = g;
    for (; j + 24 < n; j += 32) {
        int s0 = sp[j], s1 = sp[j + 8], s2 = sp[j + 16], s3 = sp[j + 24];
        float v0 = h2s[(size_t)s0 * OUT_F + f];
        float v1 = h2s[(size_t)s1 * OUT_F + f];
        float v2 = h2s[(size_t)s2 * OUT_F + f];
        float v3 = h2s[(size_t)s3 * OUT_F + f];
        acc += v0 + v1 + v2 + v3;
    }
    for (; j < n; j += 8) acc += h2s[(size_t)sp[j] * OUT_F + f];
    acc += __shfl_xor(acc, 8);
    acc += __shfl_xor(acc, 16);
    acc += __shfl_xor(acc, 32);
    acc += h2s[(size_t)wid * OUT_F + f];
    acc = fmaf(acc, dv, b2[f]);
    float m = acc;
    m = fmaxf(m, __shfl_xor(m, 1));
    m = fmaxf(m, __shfl_xor(m, 2));
    m = fmaxf(m, __shfl_xor(m, 4));
    float e = expf(acc - m);
    float ssum = e;
    ssum += __shfl_xor(ssum, 1);
    ssum += __shfl_xor(ssum, 2);
    ssum += __shfl_xor(ssum, 4);
    float res = acc - m - logf(ssum);
    if (lane < 8) out[(size_t)wid * OUT_F + lane] = res;
}

// ---------------------------------------------------------------------------
extern "C" void kernel_launch(void* const* d_in, const int* in_sizes, int n_in,
                              void* d_out, int out_size, void* d_ws, size_t ws_size,
                              hipStream_t stream) {
    const float* x   = (const float*)d_in[0];
    const int*   ei  = (const int*)d_in[1];     // [2, E] flat: src then dst
    const float* W1  = (const float*)d_in[2];
    const float* b1  = (const float*)d_in[3];
    const float* W2  = (const float*)d_in[4];
    const float* b2  = (const float*)d_in[5];
    float* out = (float*)d_out;

    const int N = N_NODES, E = N_EDGES;
    const int* src = ei;
    const int* dst = ei + E;

    char* p = (char*)d_ws;
    auto carve = [&](size_t bytes) -> void* {
        void* r = (void*)p;
        p += (bytes + 511) & ~(size_t)511;
        return r;
    };
    int*      gcnt  = (int*)carve((size_t)NB * 64 * 4);
    int*      gcur  = (int*)carve((size_t)NB * 64 * 4);
    int*      bbase = (int*)carve((size_t)(NB + 1) * 4);
    uint32_t* epk   = (uint32_t*)carve((size_t)E * 4);
    int*      offs  = (int*)carve((size_t)N * 4);
    int*      cnt   = (int*)carve((size_t)N * 4);
    float*    dinv  = (float*)carve((size_t)N * 4);
    int*      ssrc  = (int*)carve((size_t)E * 4);
    ushort*   wbf   = (ushort*)carve((size_t)HID * IN_F * 2);
    uint32_t* hs8   = (uint32_t*)carve((size_t)N * 32 * 4);   // fp8 rows, 128B
    float*    h2s   = (float*)carve((size_t)N * OUT_F * 4);

    hipMemsetAsync(gcnt, 0, (size_t)NB * 64 * 4, stream);

    k_wcast<<<8, 256, 0, stream>>>(W1, wbf);
    k_bhist<<<512, 256, 0, stream>>>(dst, gcnt, E);
    k_bscan<<<1, 512, 0, stream>>>(gcnt, bbase, gcur);
    k_part<<<(E + PASS - 1) / PASS, 512, 0, stream>>>(src, dst, gcur, epk, E);
    k_csr<<<NB, 1024, 0, stream>>>(epk, bbase, offs, cnt, dinv, ssrc, N);

    k_gemm1<<<(N + 63) / 64, 256, 0, stream>>>(x, wbf, dinv, hs8, N);
    k_agg1<<<(N * 64 + 255) / 256, 256, 0, stream>>>(hs8, offs, cnt, dinv, ssrc, b1, W2, h2s, N);
    k_agg2<<<(N * 64 + 255) / 256, 256, 0, stream>>>(h2s, offs, cnt, dinv, ssrc, b2, out, N);
}

// Round 8
// 391.391 us; speedup vs baseline: 1.0243x; 1.0243x over previous
//
#include <hip/hip_runtime.h>
#include <hip/hip_bf16.h>
#include <stdint.h>

#define N_NODES 100000
#define N_EDGES 3200000
#define IN_F 256
#define HID 128
#define OUT_F 8

#define NB   391        // node buckets of 256
#define PASS 6144       // edges staged per k_part block (33KB LDS -> 4 blk/CU)
#define CAP  10240      // k_csr LDS stage capacity

typedef short short8 __attribute__((ext_vector_type(8)));
typedef float f32x4 __attribute__((ext_vector_type(4)));
typedef float f32x2 __attribute__((ext_vector_type(2)));

// bf16 pack helpers (RNE)
__device__ __forceinline__ uint32_t pk_bf16(float a, float b) {
    uint32_t ua = __float_as_uint(a);
    uint32_t ub = __float_as_uint(b);
    ua = (ua + 0x7fff + ((ua >> 16) & 1)) >> 16;
    ub = (ub + 0x7fff + ((ub >> 16) & 1)) & 0xffff0000u;
    return ua | ub;
}

// ---------------------------------------------------------------------------
// Bucket histogram (LDS-aggregated, int4 edge reads)
// ---------------------------------------------------------------------------
__global__ __launch_bounds__(256) void k_bhist(const int* __restrict__ dst,
                                               int* __restrict__ gcnt, int E) {
    __shared__ int lb[NB];
    for (int i = threadIdx.x; i < NB; i += 256) lb[i] = 0;
    __syncthreads();
    int stride = gridDim.x * 256;
    const int4* d4 = (const int4*)dst;
    for (int e = blockIdx.x * 256 + threadIdx.x; e < E / 4; e += stride) {
        int4 d = d4[e];
        atomicAdd(&lb[d.x >> 8], 1);
        atomicAdd(&lb[d.y >> 8], 1);
        atomicAdd(&lb[d.z >> 8], 1);
        atomicAdd(&lb[d.w >> 8], 1);
    }
    __syncthreads();
    for (int i = threadIdx.x; i < NB; i += 256) {
        int c = lb[i];
        if (c) atomicAdd(&gcnt[i * 64], c);
    }
}

__global__ __launch_bounds__(512) void k_bscan(const int* __restrict__ gcnt,
                                               int* __restrict__ bbase,
                                               int* __restrict__ gcur) {
    __shared__ int sc[512];
    int tid = threadIdx.x;
    int v = (tid < NB) ? gcnt[tid * 64] : 0;
    sc[tid] = v;
    __syncthreads();
    for (int d = 1; d < 512; d <<= 1) {
        int t = (tid >= d) ? sc[tid - d] : 0;
        __syncthreads();
        sc[tid] += t;
        __syncthreads();
    }
    int excl = sc[tid] - v;
    if (tid <= NB) bbase[tid] = excl;
    if (tid < NB) gcur[tid * 64] = excl;
}

// ---------------------------------------------------------------------------
// Partition edges into bucket-contiguous regions (LDS-staged flush), 512 thr
// ---------------------------------------------------------------------------
__global__ __launch_bounds__(512) void k_part(const int* __restrict__ src,
                                              const int* __restrict__ dst,
                                              int* __restrict__ gcur,
                                              uint32_t* __restrict__ epk, int E) {
    __shared__ int lcnt[NB], loff[NB], ladj[NB], lcur[NB];
    __shared__ int sc[512];
    __shared__ uint32_t stage[PASS];
    int tid = threadIdx.x;
    int e0 = blockIdx.x * PASS;

    for (int i = tid; i < NB; i += 512) { lcnt[i] = 0; lcur[i] = 0; }
    __syncthreads();
    for (int i = tid; i < PASS; i += 512) {
        int e = e0 + i;
        if (e < E) atomicAdd(&lcnt[dst[e] >> 8], 1);
    }
    __syncthreads();
    int v = (tid < NB) ? lcnt[tid] : 0;
    sc[tid] = v;
    __syncthreads();
    for (int d = 1; d < 512; d <<= 1) {
        int t = (tid >= d) ? sc[tid - d] : 0;
        __syncthreads();
        sc[tid] += t;
        __syncthreads();
    }
    if (tid < NB) loff[tid] = sc[tid] - v;
    __syncthreads();
    if (tid < NB) {
        int len = lcnt[tid];
        if (len > 0) ladj[tid] = atomicAdd(&gcur[tid * 64], len);
    }
    __syncthreads();
    for (int i = tid; i < PASS; i += 512) {
        int e = e0 + i;
        if (e < E) {
            int d = dst[e];
            int b = d >> 8;
            int r = atomicAdd(&lcur[b], 1);
            stage[loff[b] + r] = (uint32_t)src[e] | ((uint32_t)(d & 255) << 17);
        }
    }
    __syncthreads();
    int wv = tid >> 6, ln = tid & 63;
    for (int b = wv; b < NB; b += 8) {
        int len = lcnt[b], lo = loff[b], gb = ladj[b];
        for (int j = ln; j < len; j += 64) epk[gb + j] = stage[lo + j];
    }
}

// ---------------------------------------------------------------------------
// Per-bucket CSR finalize: offs/cnt/dinv + node-sorted ssrc. 1024 threads.
// ---------------------------------------------------------------------------
__global__ __launch_bounds__(1024) void k_csr(const uint32_t* __restrict__ epk,
                                              const int* __restrict__ bbase,
                                              int* __restrict__ offs,
                                              int* __restrict__ cnt,
                                              float* __restrict__ dinv,
                                              int* __restrict__ ssrc, int N) {
    __shared__ int lcnt[256], lcur[256], loff[256];
    __shared__ uint32_t stage[CAP];
    int tid = threadIdx.x, b = blockIdx.x;
    int base = bbase[b], m = bbase[b + 1] - base;

    if (tid < 256) lcnt[tid] = 0;
    __syncthreads();
    for (int i = tid; i < m; i += 1024)
        atomicAdd(&lcnt[(epk[base + i] >> 17) & 255], 1);
    __syncthreads();
    int v = (tid < 256) ? lcnt[tid] : 0;
    if (tid < 256) loff[tid] = v;
    __syncthreads();
    for (int d = 1; d < 256; d <<= 1) {
        int t = (tid >= d && tid < 256) ? loff[tid - d] : 0;
        __syncthreads();
        if (tid < 256) loff[tid] += t;
        __syncthreads();
    }
    int excl = (tid < 256) ? (loff[tid] - v) : 0;
    __syncthreads();
    if (tid < 256) {
        loff[tid] = excl;
        lcur[tid] = 0;
        int node = b * 256 + tid;
        if (node < N) {
            offs[node] = base + excl;
            cnt[node] = v;
            dinv[node] = rsqrtf((float)(v + 1));
        }
    }
    __syncthreads();
    if (m <= CAP) {
        for (int i = tid; i < m; i += 1024) {
            uint32_t u = epk[base + i];
            int ld = (u >> 17) & 255;
            int r = atomicAdd(&lcur[ld], 1);
            stage[loff[ld] + r] = u & 0x1FFFF;
        }
        __syncthreads();
        for (int i = tid; i < m; i += 1024) ssrc[base + i] = (int)stage[i];
    } else {
        for (int i = tid; i < m; i += 1024) {
            uint32_t u = epk[base + i];
            int ld = (u >> 17) & 255;
            int r = atomicAdd(&lcur[ld], 1);
            ssrc[base + loff[ld] + r] = (int)(u & 0x1FFFF);
        }
    }
}

// ---------------------------------------------------------------------------
// W1 [256][128] fp32 -> W1bf [128][256] bf16 (transposed, n-major)
// ---------------------------------------------------------------------------
__global__ __launch_bounds__(256) void k_wcast(const float* __restrict__ W1,
                                               ushort* __restrict__ Wbf) {
    __shared__ ushort T[128][33];
    int t = threadIdx.x;
    int k0 = blockIdx.x * 32;
    for (int idx = t; idx < 32 * 128; idx += 256) {
        int k = idx >> 7, n = idx & 127;
        uint32_t uv = __float_as_uint(W1[(size_t)(k0 + k) * HID + n]);
        uv = (uv + 0x7fff + ((uv >> 16) & 1)) >> 16;
        T[n][k] = (ushort)uv;
    }
    __syncthreads();
    for (int idx = t; idx < 32 * 128; idx += 256) {
        int n = idx >> 5, k = idx & 31;
        Wbf[(size_t)n * IN_F + k0 + k] = T[n][k];
    }
}

// ---------------------------------------------------------------------------
// GEMM1 (MFMA bf16): Hs8[100000][128](fp8 e4m3) = (X @ W1) * dinv[row]
// ---------------------------------------------------------------------------
__global__ __launch_bounds__(256) void k_gemm1(const float* __restrict__ X,
                                               const ushort* __restrict__ Wbf,
                                               const float* __restrict__ dinv,
                                               uint32_t* __restrict__ Hs8, int M) {
    __shared__ uint32_t As[64 * 20];    // 64 rows x 40 bf16
    __shared__ uint32_t Bs[128 * 20];   // 128 n-rows x 40 bf16
    __shared__ float st[4][16 * 132];   // per-wave epilogue stage
    int t = threadIdx.x;
    int lane = t & 63, w = t >> 6;
    int q = lane >> 4, c16 = lane & 15;
    int row0 = blockIdx.x * 64;

    int ar = t >> 2, a4 = (t & 3);
    int grow = row0 + ar; if (grow >= M) grow = M - 1;
    const float* xrow = X + (size_t)grow * IN_F;
    int bn = t >> 1, b1h = (t & 1);
    const ushort* wrow = Wbf + (size_t)bn * IN_F;

    f32x4 acc[8];
    #pragma unroll
    for (int j = 0; j < 8; j++) acc[j] = (f32x4){0.f, 0.f, 0.f, 0.f};

    for (int kc = 0; kc < IN_F; kc += 32) {
        float4 x0 = *(const float4*)(xrow + kc + a4 * 8);
        float4 x1 = *(const float4*)(xrow + kc + a4 * 8 + 4);
        uint4 wv0 = *(const uint4*)(wrow + kc + b1h * 16);
        uint4 wv1 = *(const uint4*)(wrow + kc + b1h * 16 + 8);
        __syncthreads();
        *(uint2*)&As[ar * 20 + a4 * 4]     = make_uint2(pk_bf16(x0.x, x0.y), pk_bf16(x0.z, x0.w));
        *(uint2*)&As[ar * 20 + a4 * 4 + 2] = make_uint2(pk_bf16(x1.x, x1.y), pk_bf16(x1.z, x1.w));
        *(uint4*)&Bs[bn * 20 + b1h * 8]     = wv0;
        *(uint4*)&Bs[bn * 20 + b1h * 8 + 4] = wv1;
        __syncthreads();
        short8 af = *(const short8*)&As[(w * 16 + c16) * 20 + q * 4];
        #pragma unroll
        for (int j = 0; j < 8; j++) {
            short8 bf = *(const short8*)&Bs[(j * 16 + c16) * 20 + q * 4];
            acc[j] = __builtin_amdgcn_mfma_f32_16x16x32_bf16(af, bf, acc[j], 0, 0, 0);
        }
    }
    float dv[4];
    #pragma unroll
    for (int r = 0; r < 4; r++) {
        int gr = row0 + w * 16 + q * 4 + r;
        dv[r] = (gr < M) ? dinv[gr] : 0.f;
    }
    #pragma unroll
    for (int j = 0; j < 8; j++)
        #pragma unroll
        for (int r = 0; r < 4; r++)
            st[w][(q * 4 + r) * 132 + j * 16 + c16] = acc[j][r] * dv[r];
    __syncthreads();
    #pragma unroll
    for (int p = 0; p < 4; p++) {
        int rr = p * 4 + q;
        int gr = row0 + w * 16 + rr;
        float4 v0 = *(const float4*)&st[w][rr * 132 + c16 * 8];
        float4 v1 = *(const float4*)&st[w][rr * 132 + c16 * 8 + 4];
        uint32_t lo = 0, hi = 0;
        lo = __builtin_amdgcn_cvt_pk_fp8_f32(v0.x, v0.y, lo, false);
        lo = __builtin_amdgcn_cvt_pk_fp8_f32(v0.z, v0.w, lo, true);
        hi = __builtin_amdgcn_cvt_pk_fp8_f32(v1.x, v1.y, hi, false);
        hi = __builtin_amdgcn_cvt_pk_fp8_f32(v1.z, v1.w, hi, true);
        if (gr < M) *(uint2*)&Hs8[(size_t)gr * 32 + c16 * 2] = make_uint2(lo, hi);
    }
}

// ---------------------------------------------------------------------------
// Aggregation layer 1 + ReLU + fused GEMM2: wave per node, fp8 rows (128B).
// Half-wave per edge, 8 loads in flight; packed f32x2 accumulate.
// Epilogue: W2 in LDS with conflict-free layout w2t[(i*8+f)*32+c]:
// lane (h,c) reads all 16 scalars from bank c (2-way half-wave alias = free).
// W2 NOT kept in registers: R7 showed loop-invariant regs choke the gather MLP.
// ---------------------------------------------------------------------------
__global__ __launch_bounds__(256) void k_agg1(const uint32_t* __restrict__ hs,
                                              const int* __restrict__ offs,
                                              const int* __restrict__ cnt,
                                              const float* __restrict__ dinv,
                                              const int* __restrict__ ssrc,
                                              const float* __restrict__ b1,
                                              const float* __restrict__ W2,
                                              float* __restrict__ h2s, int N) {
    __shared__ float w2t[4 * OUT_F * 32];   // [(i*8+f)*32 + c] = W2[4c+i][f]
    int t = threadIdx.x;
    #pragma unroll
    for (int idx = t; idx < 1024; idx += 256) {
        int c = idx & 31, r = idx >> 5;     // r = i*8+f
        int i = r >> 3, f = r & 7;
        w2t[idx] = W2[(4 * c + i) * OUT_F + f];   // LDS write bank = idx%32: conflict-free
    }
    __syncthreads();
    int wid = (blockIdx.x * 256 + t) >> 6;
    int lane = t & 63;
    if (wid >= N) return;
    int h = lane >> 5, c = lane & 31;
    int f0 = h * 4;
    float dv = dinv[wid];
    f32x2 s01 = {0.f, 0.f}, s23 = {0.f, 0.f};
    if (h == 0) {
        uint32_t u = hs[(size_t)wid * 32 + c];
        s01 = __builtin_amdgcn_cvt_pk_f32_fp8(u, false);
        s23 = __builtin_amdgcn_cvt_pk_f32_fp8(u, true);
    }
    int beg = offs[wid], n = cnt[wid];
    const int* sp = ssrc + beg;
    int j = h;
    for (; j + 14 < n; j += 16) {
        int e0 = sp[j],      e1 = sp[j + 2],  e2 = sp[j + 4],  e3 = sp[j + 6];
        int e4 = sp[j + 8],  e5 = sp[j + 10], e6 = sp[j + 12], e7 = sp[j + 14];
        uint32_t u0 = hs[(size_t)e0 * 32 + c];
        uint32_t u1 = hs[(size_t)e1 * 32 + c];
        uint32_t u2 = hs[(size_t)e2 * 32 + c];
        uint32_t u3 = hs[(size_t)e3 * 32 + c];
        uint32_t u4 = hs[(size_t)e4 * 32 + c];
        uint32_t u5 = hs[(size_t)e5 * 32 + c];
        uint32_t u6 = hs[(size_t)e6 * 32 + c];
        uint32_t u7 = hs[(size_t)e7 * 32 + c];
        s01 += __builtin_amdgcn_cvt_pk_f32_fp8(u0, false); s23 += __builtin_amdgcn_cvt_pk_f32_fp8(u0, true);
        s01 += __builtin_amdgcn_cvt_pk_f32_fp8(u1, false); s23 += __builtin_amdgcn_cvt_pk_f32_fp8(u1, true);
        s01 += __builtin_amdgcn_cvt_pk_f32_fp8(u2, false); s23 += __builtin_amdgcn_cvt_pk_f32_fp8(u2, true);
        s01 += __builtin_amdgcn_cvt_pk_f32_fp8(u3, false); s23 += __builtin_amdgcn_cvt_pk_f32_fp8(u3, true);
        s01 += __builtin_amdgcn_cvt_pk_f32_fp8(u4, false); s23 += __builtin_amdgcn_cvt_pk_f32_fp8(u4, true);
        s01 += __builtin_amdgcn_cvt_pk_f32_fp8(u5, false); s23 += __builtin_amdgcn_cvt_pk_f32_fp8(u5, true);
        s01 += __builtin_amdgcn_cvt_pk_f32_fp8(u6, false); s23 += __builtin_amdgcn_cvt_pk_f32_fp8(u6, true);
        s01 += __builtin_amdgcn_cvt_pk_f32_fp8(u7, false); s23 += __builtin_amdgcn_cvt_pk_f32_fp8(u7, true);
    }
    for (; j + 6 < n; j += 8) {
        int e0 = sp[j], e1 = sp[j + 2], e2 = sp[j + 4], e3 = sp[j + 6];
        uint32_t u0 = hs[(size_t)e0 * 32 + c];
        uint32_t u1 = hs[(size_t)e1 * 32 + c];
        uint32_t u2 = hs[(size_t)e2 * 32 + c];
        uint32_t u3 = hs[(size_t)e3 * 32 + c];
        s01 += __builtin_amdgcn_cvt_pk_f32_fp8(u0, false); s23 += __builtin_amdgcn_cvt_pk_f32_fp8(u0, true);
        s01 += __builtin_amdgcn_cvt_pk_f32_fp8(u1, false); s23 += __builtin_amdgcn_cvt_pk_f32_fp8(u1, true);
        s01 += __builtin_amdgcn_cvt_pk_f32_fp8(u2, false); s23 += __builtin_amdgcn_cvt_pk_f32_fp8(u2, true);
        s01 += __builtin_amdgcn_cvt_pk_f32_fp8(u3, false); s23 += __builtin_amdgcn_cvt_pk_f32_fp8(u3, true);
    }
    for (; j < n; j += 2) {
        uint32_t u = hs[(size_t)sp[j] * 32 + c];
        s01 += __builtin_amdgcn_cvt_pk_f32_fp8(u, false);
        s23 += __builtin_amdgcn_cvt_pk_f32_fp8(u, true);
    }
    // combine halves (both halves end with identical full sums)
    s01[0] += __shfl_xor(s01[0], 32);
    s01[1] += __shfl_xor(s01[1], 32);
    s23[0] += __shfl_xor(s23[0], 32);
    s23[1] += __shfl_xor(s23[1], 32);
    // bias + ReLU (fp32)
    float4 bb = *(const float4*)(b1 + c * 4);
    float o0 = fmaxf(fmaf(s01[0], dv, bb.x), 0.f);
    float o1 = fmaxf(fmaf(s01[1], dv, bb.y), 0.f);
    float o2 = fmaxf(fmaf(s23[0], dv, bb.z), 0.f);
    float o3 = fmaxf(fmaf(s23[1], dv, bb.w), 0.f);
    // fused GEMM2 partial from LDS (bank c only): p[f] = sum_i o_i*W2[4c+i][f0+f]
    float p0 = o0 * w2t[(0 * 8 + f0 + 0) * 32 + c] + o1 * w2t[(1 * 8 + f0 + 0) * 32 + c]
             + o2 * w2t[(2 * 8 + f0 + 0) * 32 + c] + o3 * w2t[(3 * 8 + f0 + 0) * 32 + c];
    float p1 = o0 * w2t[(0 * 8 + f0 + 1) * 32 + c] + o1 * w2t[(1 * 8 + f0 + 1) * 32 + c]
             + o2 * w2t[(2 * 8 + f0 + 1) * 32 + c] + o3 * w2t[(3 * 8 + f0 + 1) * 32 + c];
    float p2 = o0 * w2t[(0 * 8 + f0 + 2) * 32 + c] + o1 * w2t[(1 * 8 + f0 + 2) * 32 + c]
             + o2 * w2t[(2 * 8 + f0 + 2) * 32 + c] + o3 * w2t[(3 * 8 + f0 + 2) * 32 + c];
    float p3 = o0 * w2t[(0 * 8 + f0 + 3) * 32 + c] + o1 * w2t[(1 * 8 + f0 + 3) * 32 + c]
             + o2 * w2t[(2 * 8 + f0 + 3) * 32 + c] + o3 * w2t[(3 * 8 + f0 + 3) * 32 + c];
    #pragma unroll
    for (int d = 1; d < 32; d <<= 1) {
        p0 += __shfl_xor(p0, d);
        p1 += __shfl_xor(p1, d);
        p2 += __shfl_xor(p2, d);
        p3 += __shfl_xor(p3, d);
    }
    if (c == 0) {
        float4 ov = make_float4(p0 * dv, p1 * dv, p2 * dv, p3 * dv);
        *(float4*)&h2s[(size_t)wid * OUT_F + f0] = ov;
    }
}

// ---------------------------------------------------------------------------
// Aggregation layer 2 + bias + log_softmax, fused; 4-deep gather MLP.
// ---------------------------------------------------------------------------
__global__ __launch_bounds__(256) void k_agg2(const float* __restrict__ h2s,
                                              const int* __restrict__ offs,
                                              const int* __restrict__ cnt,
                                              const float* __restrict__ dinv,
                                              const int* __restrict__ ssrc,
                                              const float* __restrict__ b2,
                                              float* __restrict__ out, int N) {
    int wid = (blockIdx.x * 256 + threadIdx.x) >> 6;
    int lane = threadIdx.x & 63;
    if (wid >= N) return;
    int f = lane & 7, g = lane >> 3;
    float dv = dinv[wid];
    int beg = offs[wid], n = cnt[wid];
    const int* sp = ssrc + beg;
    float acc = 0.f;
    int j = g;
    for (; j + 24 < n; j += 32) {
        int s0 = sp[j], s1 = sp[j + 8], s2 = sp[j + 16], s3 = sp[j + 24];
        float v0 = h2s[(size_t)s0 * OUT_F + f];
        float v1 = h2s[(size_t)s1 * OUT_F + f];
        float v2 = h2s[(size_t)s2 * OUT_F + f];
        float v3 = h2s[(size_t)s3 * OUT_F + f];
        acc += v0 + v1 + v2 + v3;
    }
    for (; j < n; j += 8) acc += h2s[(size_t)sp[j] * OUT_F + f];
    acc += __shfl_xor(acc, 8);
    acc += __shfl_xor(acc, 16);
    acc += __shfl_xor(acc, 32);
    acc += h2s[(size_t)wid * OUT_F + f];
    acc = fmaf(acc, dv, b2[f]);
    float m = acc;
    m = fmaxf(m, __shfl_xor(m, 1));
    m = fmaxf(m, __shfl_xor(m, 2));
    m = fmaxf(m, __shfl_xor(m, 4));
    float e = expf(acc - m);
    float ssum = e;
    ssum += __shfl_xor(ssum, 1);
    ssum += __shfl_xor(ssum, 2);
    ssum += __shfl_xor(ssum, 4);
    float res = acc - m - logf(ssum);
    if (lane < 8) out[(size_t)wid * OUT_F + lane] = res;
}

// ---------------------------------------------------------------------------
extern "C" void kernel_launch(void* const* d_in, const int* in_sizes, int n_in,
                              void* d_out, int out_size, void* d_ws, size_t ws_size,
                              hipStream_t stream) {
    const float* x   = (const float*)d_in[0];
    const int*   ei  = (const int*)d_in[1];     // [2, E] flat: src then dst
    const float* W1  = (const float*)d_in[2];
    const float* b1  = (const float*)d_in[3];
    const float* W2  = (const float*)d_in[4];
    const float* b2  = (const float*)d_in[5];
    float* out = (float*)d_out;

    const int N = N_NODES, E = N_EDGES;
    const int* src = ei;
    const int* dst = ei + E;

    char* p = (char*)d_ws;
    auto carve = [&](size_t bytes) -> void* {
        void* r = (void*)p;
        p += (bytes + 511) & ~(size_t)511;
        return r;
    };
    int*      gcnt  = (int*)carve((size_t)NB * 64 * 4);
    int*      gcur  = (int*)carve((size_t)NB * 64 * 4);
    int*      bbase = (int*)carve((size_t)(NB + 1) * 4);
    uint32_t* epk   = (uint32_t*)carve((size_t)E * 4);
    int*      offs  = (int*)carve((size_t)N * 4);
    int*      cnt   = (int*)carve((size_t)N * 4);
    float*    dinv  = (float*)carve((size_t)N * 4);
    int*      ssrc  = (int*)carve((size_t)E * 4);
    ushort*   wbf   = (ushort*)carve((size_t)HID * IN_F * 2);
    uint32_t* hs8   = (uint32_t*)carve((size_t)N * 32 * 4);   // fp8 rows, 128B
    float*    h2s   = (float*)carve((size_t)N * OUT_F * 4);

    hipMemsetAsync(gcnt, 0, (size_t)NB * 64 * 4, stream);

    k_wcast<<<8, 256, 0, stream>>>(W1, wbf);
    k_bhist<<<512, 256, 0, stream>>>(dst, gcnt, E);
    k_bscan<<<1, 512, 0, stream>>>(gcnt, bbase, gcur);
    k_part<<<(E + PASS - 1) / PASS, 512, 0, stream>>>(src, dst, gcur, epk, E);
    k_csr<<<NB, 1024, 0, stream>>>(epk, bbase, offs, cnt, dinv, ssrc, N);

    k_gemm1<<<(N + 63) / 64, 256, 0, stream>>>(x, wbf, dinv, hs8, N);
    k_agg1<<<(N * 64 + 255) / 256, 256, 0, stream>>>(hs8, offs, cnt, dinv, ssrc, b1, W2, h2s, N);
    k_agg2<<<(N * 64 + 255) / 256, 256, 0, stream>>>(h2s, offs, cnt, dinv, ssrc, b2, out, N);
}